// Round 3
// baseline (454.256 us; speedup 1.0000x reference)
//
#include <hip/hip_runtime.h>

#define PP 16
#define NN 128
#define CC 256
#define SS 64
#define HH 64

typedef __attribute__((ext_vector_type(8))) short v8bf;
typedef __attribute__((ext_vector_type(16))) float f32x16;
typedef __attribute__((ext_vector_type(4))) unsigned short u16x4;

__device__ __forceinline__ unsigned short f2bf(float f) {
    unsigned u = __float_as_uint(f);
    return (unsigned short)((u + 0x7fffu + ((u >> 16) & 1u)) >> 16);
}

// ---------------- weight repack kernels (bf16, 32x32x16 MFMA A-fragment order) ----------------
// A-frag (32x32x16): lane l holds A[m = l&31][k = 8*(l>>5)+j], j=0..7.
// wp1 frag idx: (((beta*16+p)*3 + tap)*16 + ks)*2 + mi ; m=hid=mi*32+(l&31), k=c=ks*16+8*(l>>5)+j
__global__ void k_pack1(const float* __restrict__ w31a, const float* __restrict__ w33a,
                        unsigned short* __restrict__ wp1) {
    int u = blockIdx.x * 256 + threadIdx.x;   // [0, 65536)
    int lane = u & 63;
    int ks   = (u >> 6) & 15;
    int mi   = (u >> 10) & 1;
    int p    = (u >> 11) & 15;
    int beta = u >> 15;
    int hid = mi * 32 + (lane & 31);
    int c0  = ks * 16 + 8 * (lane >> 5);
    const float* src = (beta ? w33a : w31a) + ((size_t)(p * 64 + hid) * 256 + c0) * 3;
    float f[24];
    #pragma unroll
    for (int i = 0; i < 6; ++i) *(float4*)(f + i * 4) = ((const float4*)src)[i];
    v8bf* dst = (v8bf*)wp1;
    #pragma unroll
    for (int tp = 0; tp < 3; ++tp) {
        v8bf r;
        #pragma unroll
        for (int j = 0; j < 8; ++j) r[j] = (short)f2bf(f[j * 3 + tp]);
        dst[(size_t)((((beta * 16 + p) * 3 + tp) * 16 + ks) * 2 + mi) * 64 + lane] = r;
    }
}

// wp31 frag idx: (p*4+ks)*8 + ct ; m=cout=ct*32+(l&31), k=hid=ks*16+8*(l>>5)+j
__global__ void k_pack31(const float* __restrict__ w31b, unsigned short* __restrict__ wp31) {
    int u = blockIdx.x * 256 + threadIdx.x;   // [0, 32768)
    int lane = u & 63;
    int ct = (u >> 6) & 7;
    int ks = (u >> 9) & 3;
    int p  = u >> 11;
    int cout = ct * 32 + (lane & 31);
    int hid0 = ks * 16 + 8 * (lane >> 5);
    const float* src = w31b + (size_t)(p * 256 + cout) * 64 + hid0;
    float f[8];
    *(float4*)(f)     = ((const float4*)src)[0];
    *(float4*)(f + 4) = ((const float4*)src)[1];
    v8bf r;
    #pragma unroll
    for (int j = 0; j < 8; ++j) r[j] = (short)f2bf(f[j]);
    ((v8bf*)wp31)[(size_t)((p * 4 + ks) * 8 + ct) * 64 + lane] = r;
}

// wp33 frag idx: ((p*3+tap)*4+ks)*8 + ct
__global__ void k_pack33(const float* __restrict__ w33b, unsigned short* __restrict__ wp33) {
    int u = blockIdx.x * 256 + threadIdx.x;   // [0, 32768)
    int lane = u & 63;
    int ct = (u >> 6) & 7;
    int ks = (u >> 9) & 3;
    int p  = u >> 11;
    int cout = ct * 32 + (lane & 31);
    int hid0 = ks * 16 + 8 * (lane >> 5);
    const float* src = w33b + ((size_t)(p * 256 + cout) * 64 + hid0) * 3;
    float f[24];
    #pragma unroll
    for (int i = 0; i < 6; ++i) *(float4*)(f + i * 4) = ((const float4*)src)[i];
    v8bf* dst = (v8bf*)wp33;
    #pragma unroll
    for (int tp = 0; tp < 3; ++tp) {
        v8bf r;
        #pragma unroll
        for (int j = 0; j < 8; ++j) r[j] = (short)f2bf(f[j * 3 + tp]);
        dst[(size_t)(((p * 3 + tp) * 4 + ks) * 8 + ct) * 64 + lane] = r;
    }
}

// ---------------- fused MFMA kernel ----------------
// LDS (bytes):
//   xb  bf16 [68][256]  @ 0      (34816)  row r = s+2 (rows 0,1,66,67 zero), 16B-slot XOR swizzle
//   hb  bf16 2x[66][64] @ 34816  (16896)  row r = s+1 (rows 0,65 zero), swizzled
//   tmp fp32 [64][64]   @ 34816  (16384)  phase-0 staging chunk, overlays hb (dead until phase 1)
#define XB_ROWB 512
#define HB_OFF 34816
#define HB_BR 8448
#define LDS_BYTES 51712

__global__ __launch_bounds__(512, 6)
void fused_mfma(const float* __restrict__ x,
                const unsigned short* __restrict__ wp1,
                const unsigned short* __restrict__ wp31,
                const unsigned short* __restrict__ wp33,
                float* __restrict__ out) {
    __shared__ __align__(16) char lds[LDS_BYTES];
    char* xb = lds;
    char* hb = lds + HB_OFF;
    float* tmp = (float*)(lds + HB_OFF);

    const int t = threadIdx.x;
    const int n = blockIdx.x, p = blockIdx.y;
    const int pn = p * NN + n;
    const int lane = t & 63;
    const int l31 = lane & 31, lhi5 = lane >> 5;
    const int w = t >> 6;
    const float4 z4 = make_float4(0.f, 0.f, 0.f, 0.f);

    // xb pad rows 0,1,66,67 (visibility ordered by first sync)
    if (t < 128) {
        int rr = t >> 5;
        int row = (rr < 2) ? rr : 64 + rr;
        *(float4*)(xb + row * XB_ROWB + (t & 31) * 16) = z4;
    }

    // ---------- phase 0: 4 chunked transpose rounds ----------
    const float4* xsrc = (const float4*)x + (size_t)pn * 4096;
    for (int ch = 0; ch < 4; ++ch) {
        #pragma unroll
        for (int i = 0; i < 2; ++i) {
            int j = t + i * 512;
            *(float4*)((char*)tmp + j * 16) = xsrc[ch * 1024 + j];
        }
        __syncthreads();
        {
            int s = t & 63, cg = t >> 6;
            unsigned short b[8];
            #pragma unroll
            for (int k2 = 0; k2 < 8; ++k2) b[k2] = f2bf(tmp[(cg * 8 + k2) * 64 + s]);
            int row = s + 2;
            int col = (2 * (ch * 64 + cg * 8)) ^ ((row & 7) << 4);
            v8bf vv;
            #pragma unroll
            for (int k2 = 0; k2 < 8; ++k2) vv[k2] = (short)b[k2];
            *(v8bf*)(xb + row * XB_ROWB + col) = vv;
        }
        __syncthreads();
    }

    // hb pad rows 0,65 both branches (tmp now dead)
    if (t < 32) {
        int br = t >> 4;
        int row = ((t >> 3) & 1) ? 65 : 0;
        *(float4*)(hb + br * HB_BR + row * 128 + (t & 7) * 16) = z4;
    }

    // ---------- phase 1: conv1 (32x32x16 MFMA) + leaky-relu -> hb ----------
    {
        const int beta = w & 1, mi = (w >> 1) & 1, ni = (w >> 2) & 1;
        const v8bf* wv = (const v8bf*)wp1;
        const size_t abase = (size_t)((beta * 16 + p) * 3) * 32 * 64 + (size_t)mi * 64 + lane;
        f32x16 acc = {};
        #pragma unroll
        for (int tp = 0; tp < 3; ++tp) {
            int r = ni * 32 + l31 + tp + 1;
            int swz = (r & 7) << 4;
            const char* xrow = xb + r * XB_ROWB;
            #pragma unroll
            for (int ks = 0; ks < 16; ++ks) {
                v8bf A = wv[abase + (size_t)(tp * 16 + ks) * 128];
                v8bf B = *(const v8bf*)(xrow + ((2 * (ks * 16 + 8 * lhi5)) ^ swz));
                acc = __builtin_amdgcn_mfma_f32_32x32x16_bf16(A, B, acc, 0, 0, 0);
            }
        }
        int r2 = ni * 32 + l31 + 1;
        int swz2 = (r2 & 7) << 4;
        char* hrow = hb + beta * HB_BR + r2 * 128;
        #pragma unroll
        for (int rg = 0; rg < 4; ++rg) {
            int hid0 = mi * 32 + 8 * rg + 4 * lhi5;
            u16x4 hv;
            #pragma unroll
            for (int q = 0; q < 4; ++q) {
                float v = acc[rg * 4 + q];
                v = v >= 0.f ? v : 0.01f * v;
                hv[q] = f2bf(v);
            }
            *(u16x4*)(hrow + ((2 * hid0) ^ swz2)) = hv;
        }
    }
    __syncthreads();

    // ---------- phase 2: conv2 (MFMA) + pooling(from xb) + gate + max over s ----------
    {
        const int ct = w;                       // c-tile 0..7 (32 cout each)
        const v8bf* w1v = (const v8bf*)wp31;
        const v8bf* w3v = (const v8bf*)wp33;
        float gm[16];
        #pragma unroll
        for (int i = 0; i < 16; ++i) gm[i] = -3.4e38f;

        #pragma unroll
        for (int ni = 0; ni < 2; ++ni) {
            const int s = ni * 32 + l31;
            // --- 3x1 logits ---
            f32x16 a31 = {};
            {
                int r = s + 1;
                int swz = (r & 7) << 4;
                const char* hrow = hb + r * 128;
                #pragma unroll
                for (int ks = 0; ks < 4; ++ks) {
                    v8bf A = w1v[(size_t)((p * 4 + ks) * 8 + ct) * 64 + lane];
                    v8bf B = *(const v8bf*)(hrow + ((2 * (ks * 16 + 8 * lhi5)) ^ swz));
                    a31 = __builtin_amdgcn_mfma_f32_32x32x16_bf16(A, B, a31, 0, 0, 0);
                }
            }
            // --- 3x3 logits ---
            f32x16 a33 = {};
            #pragma unroll
            for (int tp = 0; tp < 3; ++tp) {
                int r = s + tp;
                int swz = (r & 7) << 4;
                const char* hrow = hb + HB_BR + r * 128;
                #pragma unroll
                for (int ks = 0; ks < 4; ++ks) {
                    v8bf A = w3v[(size_t)(((p * 3 + tp) * 4 + ks) * 8 + ct) * 64 + lane];
                    v8bf B = *(const v8bf*)(hrow + ((2 * (ks * 16 + 8 * lhi5)) ^ swz));
                    a33 = __builtin_amdgcn_mfma_f32_32x32x16_bf16(A, B, a33, 0, 0, 0);
                }
            }
            // --- epilogue: pooling + sigmoid gate ---
            #pragma unroll
            for (int rg = 0; rg < 4; ++rg) {
                int c0 = ct * 32 + 8 * rg + 4 * lhi5;
                float q[5][4];
                #pragma unroll
                for (int d = 0; d < 5; ++d) {
                    int r = s + d;                  // = (s + (d-2)) + 2
                    u16x4 hv = *(const u16x4*)(xb + r * XB_ROWB + ((2 * c0) ^ ((r & 7) << 4)));
                    #pragma unroll
                    for (int qi = 0; qi < 4; ++qi)
                        q[d][qi] = __uint_as_float((unsigned)hv[qi] << 16);
                }
                #pragma unroll
                for (int qi = 0; qi < 4; ++qi) {
                    int reg = rg * 4 + qi;
                    float xm2 = q[0][qi], xm = q[1][qi], x0 = q[2][qi], xp = q[3][qi], xp2 = q[4][qi];
                    float s3 = (xm + x0 + xp) * (1.f / 3.f);
                    float s5 = (xm2 + xm + x0 + xp + xp2) * 0.2f;
                    float m3 = x0;
                    if (s >= 1)  m3 = fmaxf(m3, xm);
                    if (s <= 62) m3 = fmaxf(m3, xp);
                    float m5 = m3;
                    if (s >= 2)  m5 = fmaxf(m5, xm2);
                    if (s <= 61) m5 = fmaxf(m5, xp2);
                    float s31 = __builtin_amdgcn_rcpf(1.f + __expf(-a31[reg]));
                    float s33 = __builtin_amdgcn_rcpf(1.f + __expf(-a33[reg]));
                    float g = (s3 + m3) * s31 + (s5 + m5) * s33;
                    gm[reg] = fmaxf(gm[reg], g);
                }
            }
        }
        // --- max over s (32 lanes per half) + store ---
        #pragma unroll
        for (int reg = 0; reg < 16; ++reg) {
            float g = gm[reg];
            #pragma unroll
            for (int off = 16; off; off >>= 1) g = fmaxf(g, __shfl_xor(g, off));
            gm[reg] = g;
        }
        if (l31 == 0) {
            float* ob = out + (size_t)pn * 256 + ct * 32 + 4 * lhi5;
            #pragma unroll
            for (int rg = 0; rg < 4; ++rg) {
                float4 o = make_float4(gm[rg * 4], gm[rg * 4 + 1], gm[rg * 4 + 2], gm[rg * 4 + 3]);
                *(float4*)(ob + 8 * rg) = o;
            }
        }
    }
}

// ---------------- fp32 fallback (only if ws too small) ----------------
#define LW 72
__global__ __launch_bounds__(512, 2)
void fused_fallback(const float* __restrict__ x,
                    const float* __restrict__ w31a, const float* __restrict__ w31b,
                    const float* __restrict__ w33a, const float* __restrict__ w33b,
                    float* __restrict__ out) {
    __shared__ float lds[(CC + HH + HH) * LW];
    float* xs = lds;
    float* h31 = lds + CC * LW;
    float* h33 = h31 + HH * LW;
    const int t = threadIdx.x;
    const int n = blockIdx.x, p = blockIdx.y;
    const int lane = t & 63;
    {
        const float4* src = (const float4*)(x + (size_t)(p * NN + n) * (CC * SS));
        #pragma unroll
        for (int i = 0; i < 8; ++i) {
            int f4 = t + i * 512;
            int c = f4 >> 4, q = f4 & 15;
            *(float4*)(xs + c * LW + 4 + q * 4) = src[f4];
        }
        if (t < 256) {
            *(float4*)(xs + t * LW) = make_float4(0.f, 0.f, 0.f, 0.f);
            *(float4*)(xs + t * LW + 68) = make_float4(0.f, 0.f, 0.f, 0.f);
        } else if (t < 320) {
            int h = t - 256;
            *(float4*)(h33 + h * LW) = make_float4(0.f, 0.f, 0.f, 0.f);
            *(float4*)(h33 + h * LW + 68) = make_float4(0.f, 0.f, 0.f, 0.f);
        }
    }
    __syncthreads();
    {
        const int grp = t >> 6;
        const int conv = grp & 1;
        const int hid0 = (grp >> 1) * 16;
        const float4* wa4 = (const float4*)((conv ? w33a : w31a) + (size_t)p * (HH * CC * 3));
        float acc[16];
        #pragma unroll
        for (int h = 0; h < 16; ++h) acc[h] = 0.f;
        for (int c4 = 0; c4 < 64; ++c4) {
            float xm[4], x0[4], xp[4];
            #pragma unroll
            for (int j = 0; j < 4; ++j) {
                const float* r = xs + (c4 * 4 + j) * LW + 4 + lane;
                xm[j] = r[-1]; x0[j] = r[0]; xp[j] = r[1];
            }
            #pragma unroll
            for (int h = 0; h < 16; ++h) {
                const float4* wp = wa4 + (hid0 + h) * 192 + c4 * 3;
                float4 w0 = wp[0], w1 = wp[1], w2 = wp[2];
                float a = acc[h];
                a += xm[0]*w0.x + x0[0]*w0.y + xp[0]*w0.z;
                a += xm[1]*w0.w + x0[1]*w1.x + xp[1]*w1.y;
                a += xm[2]*w1.z + x0[2]*w1.w + xp[2]*w2.x;
                a += xm[3]*w2.y + x0[3]*w2.z + xp[3]*w2.w;
                acc[h] = a;
            }
        }
        float* dst = conv ? h33 : h31;
        #pragma unroll
        for (int h = 0; h < 16; ++h) {
            float v = acc[h];
            v = v >= 0.f ? v : 0.01f * v;
            dst[(hid0 + h) * LW + 4 + lane] = v;
        }
    }
    __syncthreads();
    {
        const int cg = t >> 6;
        const int c0 = cg * 32;
        float l31[32], l33[32];
        #pragma unroll
        for (int i = 0; i < 32; ++i) { l31[i] = 0.f; l33[i] = 0.f; }
        for (int hid = 0; hid < HH; ++hid) {
            const float* hr1 = h31 + hid * LW + 4 + lane;
            const float* hr3 = h33 + hid * LW + 4 + lane;
            float hv = hr1[0];
            float hm = hr3[-1], h0 = hr3[0], hp = hr3[1];
            #pragma unroll
            for (int i = 0; i < 32; ++i) {
                int c = c0 + i;
                l31[i] += hv * w31b[((size_t)p * 256 + c) * 64 + hid];
                const float* wb = w33b + (((size_t)p * 256 + c) * 64 + hid) * 3;
                l33[i] += hm * wb[0] + h0 * wb[1] + hp * wb[2];
            }
        }
        const size_t obase = ((size_t)p * NN + n) * CC + c0;
        #pragma unroll
        for (int i = 0; i < 32; ++i) {
            const float* r = xs + (c0 + i) * LW + 4 + lane;
            float xm2 = r[-2], xm = r[-1], x0v = r[0], xp = r[1], xp2 = r[2];
            float s3 = (xm + x0v + xp) * (1.f / 3.f);
            float s5 = (xm2 + xm + x0v + xp + xp2) * 0.2f;
            float m3 = x0v;
            if (lane >= 1)  m3 = fmaxf(m3, xm);
            if (lane <= 62) m3 = fmaxf(m3, xp);
            float m5 = m3;
            if (lane >= 2)  m5 = fmaxf(m5, xm2);
            if (lane <= 61) m5 = fmaxf(m5, xp2);
            float g = (s3 + m3) / (1.f + __expf(-l31[i])) + (s5 + m5) / (1.f + __expf(-l33[i]));
            #pragma unroll
            for (int off = 32; off; off >>= 1)
                g = fmaxf(g, __shfl_xor(g, off));
            if (lane == 0) out[obase + i] = g;
        }
    }
}

extern "C" void kernel_launch(void* const* d_in, const int* in_sizes, int n_in,
                              void* d_out, int out_size, void* d_ws, size_t ws_size,
                              hipStream_t stream) {
    const float* x    = (const float*)d_in[0];
    const float* w31a = (const float*)d_in[1];
    const float* w31b = (const float*)d_in[2];
    const float* w33a = (const float*)d_in[3];
    const float* w33b = (const float*)d_in[4];
    float* out = (float*)d_out;

    // ws: wp1 @0 (3,145,728 B), wp31 @3,145,728 (524,288 B), wp33 @3,670,016 (1,572,864 B)
    const size_t need = 5242880;
    dim3 grid(NN, PP);
    if (ws_size >= need) {
        unsigned short* wp1  = (unsigned short*)d_ws;
        unsigned short* wp31 = (unsigned short*)((char*)d_ws + 3145728);
        unsigned short* wp33 = (unsigned short*)((char*)d_ws + 3670016);
        k_pack1 <<<256, 256, 0, stream>>>(w31a, w33a, wp1);
        k_pack31<<<128, 256, 0, stream>>>(w31b, wp31);
        k_pack33<<<128, 256, 0, stream>>>(w33b, wp33);
        fused_mfma<<<grid, 512, 0, stream>>>(x, wp1, wp31, wp33, out);
    } else {
        fused_fallback<<<grid, 512, 0, stream>>>(x, w31a, w31b, w33a, w33b, out);
    }
}

// Round 4
// 262.087 us; speedup vs baseline: 1.7332x; 1.7332x over previous
//
#include <hip/hip_runtime.h>

#define PP 16
#define NN 128
#define CC 256
#define SS 64
#define HH 64

typedef __attribute__((ext_vector_type(8))) short v8bf;
typedef __attribute__((ext_vector_type(16))) float f32x16;
typedef __attribute__((ext_vector_type(4))) unsigned short u16x4;

__device__ __forceinline__ unsigned short f2bf(float f) {
    unsigned u = __float_as_uint(f);
    return (unsigned short)((u + 0x7fffu + ((u >> 16) & 1u)) >> 16);
}

// ---------------- single weight-repack kernel (bf16, 32x32x16 A-fragment order) ----------------
// A-frag: lane l holds A[m = l&31][k = 8*(l>>5)+j], j=0..7.
// wp1  frag idx (((beta*16+p)*3 + tap)*16 + ks)*2 + mi : m=hid=mi*32+(l&31), k=c=ks*16+8*(l>>5)+j
// wp31 frag idx (p*4+ks)*8 + ct                        : m=cout=ct*32+(l&31), k=hid=ks*16+8*(l>>5)+j
// wp33 frag idx ((p*3+tap)*4+ks)*8 + ct
__global__ void k_pack_all(const float* __restrict__ w31a, const float* __restrict__ w33a,
                           const float* __restrict__ w31b, const float* __restrict__ w33b,
                           unsigned short* __restrict__ wp1,
                           unsigned short* __restrict__ wp31,
                           unsigned short* __restrict__ wp33) {
    int b = blockIdx.x;
    int t = threadIdx.x;
    if (b < 256) {                                 // ---- pack conv1 weights ----
        int u = b * 256 + t;                       // [0, 65536)
        int lane = u & 63;
        int ks   = (u >> 6) & 15;
        int mi   = (u >> 10) & 1;
        int p    = (u >> 11) & 15;
        int beta = u >> 15;
        int hid = mi * 32 + (lane & 31);
        int c0  = ks * 16 + 8 * (lane >> 5);
        const float* src = (beta ? w33a : w31a) + ((size_t)(p * 64 + hid) * 256 + c0) * 3;
        float f[24];
        #pragma unroll
        for (int i = 0; i < 6; ++i) *(float4*)(f + i * 4) = ((const float4*)src)[i];
        v8bf* dst = (v8bf*)wp1;
        #pragma unroll
        for (int tp = 0; tp < 3; ++tp) {
            v8bf r;
            #pragma unroll
            for (int j = 0; j < 8; ++j) r[j] = (short)f2bf(f[j * 3 + tp]);
            dst[(size_t)((((beta * 16 + p) * 3 + tp) * 16 + ks) * 2 + mi) * 64 + lane] = r;
        }
    } else if (b < 384) {                          // ---- pack w31_b ----
        int u = (b - 256) * 256 + t;               // [0, 32768)
        int lane = u & 63;
        int ct = (u >> 6) & 7;
        int ks = (u >> 9) & 3;
        int p  = u >> 11;
        int cout = ct * 32 + (lane & 31);
        int hid0 = ks * 16 + 8 * (lane >> 5);
        const float* src = w31b + (size_t)(p * 256 + cout) * 64 + hid0;
        float f[8];
        *(float4*)(f)     = ((const float4*)src)[0];
        *(float4*)(f + 4) = ((const float4*)src)[1];
        v8bf r;
        #pragma unroll
        for (int j = 0; j < 8; ++j) r[j] = (short)f2bf(f[j]);
        ((v8bf*)wp31)[(size_t)((p * 4 + ks) * 8 + ct) * 64 + lane] = r;
    } else {                                       // ---- pack w33_b ----
        int u = (b - 384) * 256 + t;               // [0, 32768)
        int lane = u & 63;
        int ct = (u >> 6) & 7;
        int ks = (u >> 9) & 3;
        int p  = u >> 11;
        int cout = ct * 32 + (lane & 31);
        int hid0 = ks * 16 + 8 * (lane >> 5);
        const float* src = w33b + ((size_t)(p * 256 + cout) * 64 + hid0) * 3;
        float f[24];
        #pragma unroll
        for (int i = 0; i < 6; ++i) *(float4*)(f + i * 4) = ((const float4*)src)[i];
        v8bf* dst = (v8bf*)wp33;
        #pragma unroll
        for (int tp = 0; tp < 3; ++tp) {
            v8bf r;
            #pragma unroll
            for (int j = 0; j < 8; ++j) r[j] = (short)f2bf(f[j * 3 + tp]);
            dst[(size_t)(((p * 3 + tp) * 4 + ks) * 8 + ct) * 64 + lane] = r;
        }
    }
}

// ---------------- fused MFMA kernel ----------------
// LDS (bytes):
//   xb  bf16 [68] rows x 512 B @ 0      (34816)  row r = s+2 (rows 0,1,66,67 zero)
//        logical col = 2*c, physical col = col ^ ((r&15)<<4)   -> 2-way on 32-row reads
//   hb  bf16 [66] rows x 256 B @ 34816  (16896)  row r = s+1 (rows 0,65 zero)
//        logical col = beta*128 + 2*hid, physical col = col ^ ((r&15)<<4)
//   tmp fp32 [64][64]          @ 34816  (16384)  phase-0 staging, overlays hb (dead until phase 1)
#define XB_ROWB 512
#define HB_OFF 34816
#define HB_ROWB 256
#define LDS_BYTES 51712

__global__ __launch_bounds__(512, 4)
void fused_mfma(const float* __restrict__ x,
                const unsigned short* __restrict__ wp1,
                const unsigned short* __restrict__ wp31,
                const unsigned short* __restrict__ wp33,
                float* __restrict__ out) {
    __shared__ __align__(16) char lds[LDS_BYTES];
    char* xb = lds;
    char* hb = lds + HB_OFF;
    float* tmp = (float*)(lds + HB_OFF);

    const int t = threadIdx.x;
    const int n = blockIdx.x, p = blockIdx.y;
    const int pn = p * NN + n;
    const int lane = t & 63;
    const int l31 = lane & 31, lhi5 = lane >> 5;
    const int w = t >> 6;
    const float4 z4 = make_float4(0.f, 0.f, 0.f, 0.f);

    // xb pad rows 0,1,66,67
    if (t < 128) {
        int rr = t >> 5;
        int row = (rr < 2) ? rr : 64 + rr;
        *(float4*)(xb + row * XB_ROWB + (t & 31) * 16) = z4;
    }

    // ---------- phase 0: 4 chunked transpose rounds ----------
    const float4* xsrc = (const float4*)x + (size_t)pn * 4096;
    for (int ch = 0; ch < 4; ++ch) {
        #pragma unroll
        for (int i = 0; i < 2; ++i) {
            int j = t + i * 512;
            *(float4*)((char*)tmp + j * 16) = xsrc[ch * 1024 + j];
        }
        __syncthreads();
        {
            int s = t & 63, cg = t >> 6;
            int row = s + 2;
            int col = (2 * (ch * 64 + cg * 8)) ^ ((row & 15) << 4);
            v8bf vv;
            #pragma unroll
            for (int k2 = 0; k2 < 8; ++k2) vv[k2] = (short)f2bf(tmp[(cg * 8 + k2) * 64 + s]);
            *(v8bf*)(xb + row * XB_ROWB + col) = vv;
        }
        __syncthreads();
    }

    // hb pad rows 0,65 (tmp now dead)
    if (t < 32) {
        int row = (t >> 4) ? 65 : 0;
        *(float4*)(hb + row * HB_ROWB + (t & 15) * 16) = z4;
    }

    // ---------- phase 1: conv1 (32x32x16 MFMA) + leaky-relu -> hb ----------
    {
        const int beta = w & 1, mi = (w >> 1) & 1, ni = (w >> 2) & 1;
        const v8bf* wv = (const v8bf*)wp1;
        const size_t abase = (size_t)((beta * 16 + p) * 3) * 32 * 64 + (size_t)mi * 64 + lane;
        f32x16 acc = {};
        #pragma unroll
        for (int tp = 0; tp < 3; ++tp) {
            int r = ni * 32 + l31 + tp + 1;
            int swz = (r & 15) << 4;
            const char* xrow = xb + r * XB_ROWB;
            #pragma unroll
            for (int ks = 0; ks < 16; ++ks) {
                v8bf A = wv[abase + (size_t)(tp * 16 + ks) * 128];
                v8bf B = *(const v8bf*)(xrow + ((2 * (ks * 16 + 8 * lhi5)) ^ swz));
                acc = __builtin_amdgcn_mfma_f32_32x32x16_bf16(A, B, acc, 0, 0, 0);
            }
        }
        int r2 = ni * 32 + l31 + 1;
        int swz2 = (r2 & 15) << 4;
        char* hrow = hb + r2 * HB_ROWB;
        #pragma unroll
        for (int rg = 0; rg < 4; ++rg) {
            int col = beta * 128 + 2 * (mi * 32 + 8 * rg + 4 * lhi5);
            u16x4 hv;
            #pragma unroll
            for (int q = 0; q < 4; ++q) {
                float v = acc[rg * 4 + q];
                v = v >= 0.f ? v : 0.01f * v;
                hv[q] = f2bf(v);
            }
            *(u16x4*)(hrow + (col ^ swz2)) = hv;
        }
    }
    __syncthreads();

    // ---------- phase 2: conv2 (MFMA) + pooling(from xb) + gate + max over s ----------
    {
        const int ct = w;                       // c-tile 0..7 (32 cout each)
        const v8bf* w1v = (const v8bf*)wp31;
        const v8bf* w3v = (const v8bf*)wp33;
        float gm[16];
        #pragma unroll
        for (int i = 0; i < 16; ++i) gm[i] = -3.4e38f;

        #pragma unroll
        for (int ni = 0; ni < 2; ++ni) {
            const int s = ni * 32 + l31;
            // --- 3x1 logits ---
            f32x16 a31 = {};
            {
                int r = s + 1;
                int swz = (r & 15) << 4;
                const char* hrow = hb + r * HB_ROWB;
                #pragma unroll
                for (int ks = 0; ks < 4; ++ks) {
                    v8bf A = w1v[(size_t)((p * 4 + ks) * 8 + ct) * 64 + lane];
                    v8bf B = *(const v8bf*)(hrow + ((2 * (ks * 16 + 8 * lhi5)) ^ swz));
                    a31 = __builtin_amdgcn_mfma_f32_32x32x16_bf16(A, B, a31, 0, 0, 0);
                }
            }
            // --- 3x3 logits ---
            f32x16 a33 = {};
            #pragma unroll
            for (int tp = 0; tp < 3; ++tp) {
                int r = s + tp;
                int swz = (r & 15) << 4;
                const char* hrow = hb + r * HB_ROWB;
                #pragma unroll
                for (int ks = 0; ks < 4; ++ks) {
                    v8bf A = w3v[(size_t)(((p * 3 + tp) * 4 + ks) * 8 + ct) * 64 + lane];
                    v8bf B = *(const v8bf*)(hrow + ((128 + 2 * (ks * 16 + 8 * lhi5)) ^ swz));
                    a33 = __builtin_amdgcn_mfma_f32_32x32x16_bf16(A, B, a33, 0, 0, 0);
                }
            }
            // --- epilogue: pooling + sigmoid gate ---
            #pragma unroll
            for (int rg = 0; rg < 4; ++rg) {
                int c0 = ct * 32 + 8 * rg + 4 * lhi5;
                float q[5][4];
                #pragma unroll
                for (int d = 0; d < 5; ++d) {
                    int r = s + d;                  // xb row for s_offset d-2
                    u16x4 hv = *(const u16x4*)(xb + r * XB_ROWB + ((2 * c0) ^ ((r & 15) << 4)));
                    #pragma unroll
                    for (int qi = 0; qi < 4; ++qi)
                        q[d][qi] = __uint_as_float((unsigned)hv[qi] << 16);
                }
                #pragma unroll
                for (int qi = 0; qi < 4; ++qi) {
                    int reg = rg * 4 + qi;
                    float xm2 = q[0][qi], xm = q[1][qi], x0 = q[2][qi], xp = q[3][qi], xp2 = q[4][qi];
                    float s3 = (xm + x0 + xp) * (1.f / 3.f);
                    float s5 = (xm2 + xm + x0 + xp + xp2) * 0.2f;
                    float m3 = x0;
                    if (s >= 1)  m3 = fmaxf(m3, xm);
                    if (s <= 62) m3 = fmaxf(m3, xp);
                    float m5 = m3;
                    if (s >= 2)  m5 = fmaxf(m5, xm2);
                    if (s <= 61) m5 = fmaxf(m5, xp2);
                    float s31 = __builtin_amdgcn_rcpf(1.f + __expf(-a31[reg]));
                    float s33 = __builtin_amdgcn_rcpf(1.f + __expf(-a33[reg]));
                    float g = (s3 + m3) * s31 + (s5 + m5) * s33;
                    gm[reg] = fmaxf(gm[reg], g);
                }
            }
        }
        // --- max over s (32 lanes per half) + store ---
        #pragma unroll
        for (int reg = 0; reg < 16; ++reg) {
            float g = gm[reg];
            #pragma unroll
            for (int off = 16; off; off >>= 1) g = fmaxf(g, __shfl_xor(g, off));
            gm[reg] = g;
        }
        if (l31 == 0) {
            float* ob = out + (size_t)pn * 256 + ct * 32 + 4 * lhi5;
            #pragma unroll
            for (int rg = 0; rg < 4; ++rg) {
                float4 o = make_float4(gm[rg * 4], gm[rg * 4 + 1], gm[rg * 4 + 2], gm[rg * 4 + 3]);
                *(float4*)(ob + 8 * rg) = o;
            }
        }
    }
}

// ---------------- fp32 fallback (only if ws too small) ----------------
#define LW 72
__global__ __launch_bounds__(512, 2)
void fused_fallback(const float* __restrict__ x,
                    const float* __restrict__ w31a, const float* __restrict__ w31b,
                    const float* __restrict__ w33a, const float* __restrict__ w33b,
                    float* __restrict__ out) {
    __shared__ float lds[(CC + HH + HH) * LW];
    float* xs = lds;
    float* h31 = lds + CC * LW;
    float* h33 = h31 + HH * LW;
    const int t = threadIdx.x;
    const int n = blockIdx.x, p = blockIdx.y;
    const int lane = t & 63;
    {
        const float4* src = (const float4*)(x + (size_t)(p * NN + n) * (CC * SS));
        #pragma unroll
        for (int i = 0; i < 8; ++i) {
            int f4 = t + i * 512;
            int c = f4 >> 4, q = f4 & 15;
            *(float4*)(xs + c * LW + 4 + q * 4) = src[f4];
        }
        if (t < 256) {
            *(float4*)(xs + t * LW) = make_float4(0.f, 0.f, 0.f, 0.f);
            *(float4*)(xs + t * LW + 68) = make_float4(0.f, 0.f, 0.f, 0.f);
        } else if (t < 320) {
            int h = t - 256;
            *(float4*)(h33 + h * LW) = make_float4(0.f, 0.f, 0.f, 0.f);
            *(float4*)(h33 + h * LW + 68) = make_float4(0.f, 0.f, 0.f, 0.f);
        }
    }
    __syncthreads();
    {
        const int grp = t >> 6;
        const int conv = grp & 1;
        const int hid0 = (grp >> 1) * 16;
        const float4* wa4 = (const float4*)((conv ? w33a : w31a) + (size_t)p * (HH * CC * 3));
        float acc[16];
        #pragma unroll
        for (int h = 0; h < 16; ++h) acc[h] = 0.f;
        for (int c4 = 0; c4 < 64; ++c4) {
            float xm[4], x0[4], xp[4];
            #pragma unroll
            for (int j = 0; j < 4; ++j) {
                const float* r = xs + (c4 * 4 + j) * LW + 4 + lane;
                xm[j] = r[-1]; x0[j] = r[0]; xp[j] = r[1];
            }
            #pragma unroll
            for (int h = 0; h < 16; ++h) {
                const float4* wp = wa4 + (hid0 + h) * 192 + c4 * 3;
                float4 w0 = wp[0], w1 = wp[1], w2 = wp[2];
                float a = acc[h];
                a += xm[0]*w0.x + x0[0]*w0.y + xp[0]*w0.z;
                a += xm[1]*w0.w + x0[1]*w1.x + xp[1]*w1.y;
                a += xm[2]*w1.z + x0[2]*w1.w + xp[2]*w2.x;
                a += xm[3]*w2.y + x0[3]*w2.z + xp[3]*w2.w;
                acc[h] = a;
            }
        }
        float* dst = conv ? h33 : h31;
        #pragma unroll
        for (int h = 0; h < 16; ++h) {
            float v = acc[h];
            v = v >= 0.f ? v : 0.01f * v;
            dst[(hid0 + h) * LW + 4 + lane] = v;
        }
    }
    __syncthreads();
    {
        const int cg = t >> 6;
        const int c0 = cg * 32;
        float l31[32], l33[32];
        #pragma unroll
        for (int i = 0; i < 32; ++i) { l31[i] = 0.f; l33[i] = 0.f; }
        for (int hid = 0; hid < HH; ++hid) {
            const float* hr1 = h31 + hid * LW + 4 + lane;
            const float* hr3 = h33 + hid * LW + 4 + lane;
            float hv = hr1[0];
            float hm = hr3[-1], h0 = hr3[0], hp = hr3[1];
            #pragma unroll
            for (int i = 0; i < 32; ++i) {
                int c = c0 + i;
                l31[i] += hv * w31b[((size_t)p * 256 + c) * 64 + hid];
                const float* wb = w33b + (((size_t)p * 256 + c) * 64 + hid) * 3;
                l33[i] += hm * wb[0] + h0 * wb[1] + hp * wb[2];
            }
        }
        const size_t obase = ((size_t)p * NN + n) * CC + c0;
        #pragma unroll
        for (int i = 0; i < 32; ++i) {
            const float* r = xs + (c0 + i) * LW + 4 + lane;
            float xm2 = r[-2], xm = r[-1], x0v = r[0], xp = r[1], xp2 = r[2];
            float s3 = (xm + x0v + xp) * (1.f / 3.f);
            float s5 = (xm2 + xm + x0v + xp + xp2) * 0.2f;
            float m3 = x0v;
            if (lane >= 1)  m3 = fmaxf(m3, xm);
            if (lane <= 62) m3 = fmaxf(m3, xp);
            float m5 = m3;
            if (lane >= 2)  m5 = fmaxf(m5, xm2);
            if (lane <= 61) m5 = fmaxf(m5, xp2);
            float g = (s3 + m3) / (1.f + __expf(-l31[i])) + (s5 + m5) / (1.f + __expf(-l33[i]));
            #pragma unroll
            for (int off = 32; off; off >>= 1)
                g = fmaxf(g, __shfl_xor(g, off));
            if (lane == 0) out[obase + i] = g;
        }
    }
}

extern "C" void kernel_launch(void* const* d_in, const int* in_sizes, int n_in,
                              void* d_out, int out_size, void* d_ws, size_t ws_size,
                              hipStream_t stream) {
    const float* x    = (const float*)d_in[0];
    const float* w31a = (const float*)d_in[1];
    const float* w31b = (const float*)d_in[2];
    const float* w33a = (const float*)d_in[3];
    const float* w33b = (const float*)d_in[4];
    float* out = (float*)d_out;

    // ws: wp1 @0 (3,145,728 B), wp31 @3,145,728 (524,288 B), wp33 @3,670,016 (1,572,864 B)
    const size_t need = 5242880;
    dim3 grid(NN, PP);
    if (ws_size >= need) {
        unsigned short* wp1  = (unsigned short*)d_ws;
        unsigned short* wp31 = (unsigned short*)((char*)d_ws + 3145728);
        unsigned short* wp33 = (unsigned short*)((char*)d_ws + 3670016);
        k_pack_all<<<512, 256, 0, stream>>>(w31a, w33a, w31b, w33b, wp1, wp31, wp33);
        fused_mfma<<<grid, 512, 0, stream>>>(x, wp1, wp31, wp33, out);
    } else {
        fused_fallback<<<grid, 512, 0, stream>>>(x, w31a, w31b, w33a, w33b, out);
    }
}

// Round 5
// 258.600 us; speedup vs baseline: 1.7566x; 1.0135x over previous
//
#include <hip/hip_runtime.h>

#define PP 16
#define NN 128
#define CC 256
#define SS 64
#define HH 64

typedef __attribute__((ext_vector_type(8))) short v8bf;
typedef __attribute__((ext_vector_type(16))) float f32x16;
typedef __attribute__((ext_vector_type(4))) unsigned short u16x4;

__device__ __forceinline__ unsigned short f2bf(float f) {
    unsigned u = __float_as_uint(f);
    return (unsigned short)((u + 0x7fffu + ((u >> 16) & 1u)) >> 16);
}

// ---------------- coalesced weight-repack kernel (bf16, 32x32x16 A-fragment order) ----------------
// A-frag: lane l holds A[m = l&31][k = 8*(l>>5)+j], j=0..7.
// wp1  frag idx (((beta*16+p)*3 + tap)*16 + ks)*2 + mi : m=hid=mi*32+(l&31), k=c=ks*16+8*(l>>5)+j
// wp31 frag idx (p*4+ks)*8 + ct                        : m=cout=ct*32+(l&31), k=hid=ks*16+8*(l>>5)+j
// wp33 frag idx ((p*3+tap)*4+ks)*8 + ct
// Thread->work mapping puts the contraction-dim block in the LOW bits of u so that
// consecutive lanes read CONSECUTIVE global spans (24 or 96 B) -> fully coalesced.
__global__ void k_pack_all(const float* __restrict__ w31a, const float* __restrict__ w33a,
                           const float* __restrict__ w31b, const float* __restrict__ w33b,
                           unsigned short* __restrict__ wp1,
                           unsigned short* __restrict__ wp31,
                           unsigned short* __restrict__ wp33) {
    int b = blockIdx.x;
    int t = threadIdx.x;
    if (b < 256) {                                 // ---- conv1 weights (w31a, w33a) ----
        int u = b * 256 + t;                       // [0, 65536) = [beta:1][p:4][hid:6][c_blk:5]
        int c_blk = u & 31;                        // c0 = c_blk*8
        int hid   = (u >> 5) & 63;
        int p     = (u >> 11) & 15;
        int beta  = u >> 15;
        const float* src = (beta ? w33a : w31a) + ((size_t)(p * 64 + hid) * 256 + c_blk * 8) * 3;
        float f[24];                               // 8 c  x 3 taps, contiguous 96 B
        #pragma unroll
        for (int i = 0; i < 6; ++i) *(float4*)(f + i * 4) = ((const float4*)src)[i];
        int ks   = c_blk >> 1;
        int lane = (hid & 31) + 32 * (c_blk & 1);
        int mi   = hid >> 5;
        v8bf* dst = (v8bf*)wp1;
        #pragma unroll
        for (int tp = 0; tp < 3; ++tp) {
            v8bf r;
            #pragma unroll
            for (int j = 0; j < 8; ++j) r[j] = (short)f2bf(f[j * 3 + tp]);
            dst[(size_t)((((beta * 16 + p) * 3 + tp) * 16 + ks) * 2 + mi) * 64 + lane] = r;
        }
    } else if (b < 384) {                          // ---- w31_b ----
        int u = (b - 256) * 256 + t;               // [0, 32768) = [p:4][cout:8][hid_blk:3]
        int hid_blk = u & 7;                       // hid0 = hid_blk*8
        int cout    = (u >> 3) & 255;
        int p       = u >> 11;
        const float* src = w31b + (size_t)(p * 256 + cout) * 64 + hid_blk * 8;
        float f[8];                                // contiguous 32 B
        *(float4*)(f)     = ((const float4*)src)[0];
        *(float4*)(f + 4) = ((const float4*)src)[1];
        int ks   = hid_blk >> 1;
        int lane = (cout & 31) + 32 * (hid_blk & 1);
        int ct   = cout >> 5;
        v8bf r;
        #pragma unroll
        for (int j = 0; j < 8; ++j) r[j] = (short)f2bf(f[j]);
        ((v8bf*)wp31)[(size_t)((p * 4 + ks) * 8 + ct) * 64 + lane] = r;
    } else {                                       // ---- w33_b ----
        int u = (b - 384) * 256 + t;               // [0, 32768) = [p:4][cout:8][hid_blk:3]
        int hid_blk = u & 7;
        int cout    = (u >> 3) & 255;
        int p       = u >> 11;
        const float* src = w33b + ((size_t)(p * 256 + cout) * 64 + hid_blk * 8) * 3;
        float f[24];                               // 8 hid x 3 taps, contiguous 96 B
        #pragma unroll
        for (int i = 0; i < 6; ++i) *(float4*)(f + i * 4) = ((const float4*)src)[i];
        int ks   = hid_blk >> 1;
        int lane = (cout & 31) + 32 * (hid_blk & 1);
        int ct   = cout >> 5;
        v8bf* dst = (v8bf*)wp33;
        #pragma unroll
        for (int tp = 0; tp < 3; ++tp) {
            v8bf r;
            #pragma unroll
            for (int j = 0; j < 8; ++j) r[j] = (short)f2bf(f[j * 3 + tp]);
            dst[(size_t)(((p * 3 + tp) * 4 + ks) * 8 + ct) * 64 + lane] = r;
        }
    }
}

// ---------------- fused MFMA kernel (unchanged from round 4) ----------------
// LDS (bytes):
//   xb  bf16 [68] rows x 512 B @ 0      (34816)  row r = s+2 (rows 0,1,66,67 zero)
//        logical col = 2*c, physical col = col ^ ((r&15)<<4)   -> 2-way on 32-row reads
//   hb  bf16 [66] rows x 256 B @ 34816  (16896)  row r = s+1 (rows 0,65 zero)
//        logical col = beta*128 + 2*hid, physical col = col ^ ((r&15)<<4)
//   tmp fp32 [64][64]          @ 34816  (16384)  phase-0 staging, overlays hb (dead until phase 1)
#define XB_ROWB 512
#define HB_OFF 34816
#define HB_ROWB 256
#define LDS_BYTES 51712

__global__ __launch_bounds__(512, 4)
void fused_mfma(const float* __restrict__ x,
                const unsigned short* __restrict__ wp1,
                const unsigned short* __restrict__ wp31,
                const unsigned short* __restrict__ wp33,
                float* __restrict__ out) {
    __shared__ __align__(16) char lds[LDS_BYTES];
    char* xb = lds;
    char* hb = lds + HB_OFF;
    float* tmp = (float*)(lds + HB_OFF);

    const int t = threadIdx.x;
    const int n = blockIdx.x, p = blockIdx.y;
    const int pn = p * NN + n;
    const int lane = t & 63;
    const int l31 = lane & 31, lhi5 = lane >> 5;
    const int w = t >> 6;
    const float4 z4 = make_float4(0.f, 0.f, 0.f, 0.f);

    // xb pad rows 0,1,66,67
    if (t < 128) {
        int rr = t >> 5;
        int row = (rr < 2) ? rr : 64 + rr;
        *(float4*)(xb + row * XB_ROWB + (t & 31) * 16) = z4;
    }

    // ---------- phase 0: 4 chunked transpose rounds ----------
    const float4* xsrc = (const float4*)x + (size_t)pn * 4096;
    for (int ch = 0; ch < 4; ++ch) {
        #pragma unroll
        for (int i = 0; i < 2; ++i) {
            int j = t + i * 512;
            *(float4*)((char*)tmp + j * 16) = xsrc[ch * 1024 + j];
        }
        __syncthreads();
        {
            int s = t & 63, cg = t >> 6;
            int row = s + 2;
            int col = (2 * (ch * 64 + cg * 8)) ^ ((row & 15) << 4);
            v8bf vv;
            #pragma unroll
            for (int k2 = 0; k2 < 8; ++k2) vv[k2] = (short)f2bf(tmp[(cg * 8 + k2) * 64 + s]);
            *(v8bf*)(xb + row * XB_ROWB + col) = vv;
        }
        __syncthreads();
    }

    // hb pad rows 0,65 (tmp now dead)
    if (t < 32) {
        int row = (t >> 4) ? 65 : 0;
        *(float4*)(hb + row * HB_ROWB + (t & 15) * 16) = z4;
    }

    // ---------- phase 1: conv1 (32x32x16 MFMA) + leaky-relu -> hb ----------
    {
        const int beta = w & 1, mi = (w >> 1) & 1, ni = (w >> 2) & 1;
        const v8bf* wv = (const v8bf*)wp1;
        const size_t abase = (size_t)((beta * 16 + p) * 3) * 32 * 64 + (size_t)mi * 64 + lane;
        f32x16 acc = {};
        #pragma unroll
        for (int tp = 0; tp < 3; ++tp) {
            int r = ni * 32 + l31 + tp + 1;
            int swz = (r & 15) << 4;
            const char* xrow = xb + r * XB_ROWB;
            #pragma unroll
            for (int ks = 0; ks < 16; ++ks) {
                v8bf A = wv[abase + (size_t)(tp * 16 + ks) * 128];
                v8bf B = *(const v8bf*)(xrow + ((2 * (ks * 16 + 8 * lhi5)) ^ swz));
                acc = __builtin_amdgcn_mfma_f32_32x32x16_bf16(A, B, acc, 0, 0, 0);
            }
        }
        int r2 = ni * 32 + l31 + 1;
        int swz2 = (r2 & 15) << 4;
        char* hrow = hb + r2 * HB_ROWB;
        #pragma unroll
        for (int rg = 0; rg < 4; ++rg) {
            int col = beta * 128 + 2 * (mi * 32 + 8 * rg + 4 * lhi5);
            u16x4 hv;
            #pragma unroll
            for (int q = 0; q < 4; ++q) {
                float v = acc[rg * 4 + q];
                v = v >= 0.f ? v : 0.01f * v;
                hv[q] = f2bf(v);
            }
            *(u16x4*)(hrow + (col ^ swz2)) = hv;
        }
    }
    __syncthreads();

    // ---------- phase 2: conv2 (MFMA) + pooling(from xb) + gate + max over s ----------
    {
        const int ct = w;                       // c-tile 0..7 (32 cout each)
        const v8bf* w1v = (const v8bf*)wp31;
        const v8bf* w3v = (const v8bf*)wp33;
        float gm[16];
        #pragma unroll
        for (int i = 0; i < 16; ++i) gm[i] = -3.4e38f;

        #pragma unroll
        for (int ni = 0; ni < 2; ++ni) {
            const int s = ni * 32 + l31;
            // --- 3x1 logits ---
            f32x16 a31 = {};
            {
                int r = s + 1;
                int swz = (r & 15) << 4;
                const char* hrow = hb + r * HB_ROWB;
                #pragma unroll
                for (int ks = 0; ks < 4; ++ks) {
                    v8bf A = w1v[(size_t)((p * 4 + ks) * 8 + ct) * 64 + lane];
                    v8bf B = *(const v8bf*)(hrow + ((2 * (ks * 16 + 8 * lhi5)) ^ swz));
                    a31 = __builtin_amdgcn_mfma_f32_32x32x16_bf16(A, B, a31, 0, 0, 0);
                }
            }
            // --- 3x3 logits ---
            f32x16 a33 = {};
            #pragma unroll
            for (int tp = 0; tp < 3; ++tp) {
                int r = s + tp;
                int swz = (r & 15) << 4;
                const char* hrow = hb + r * HB_ROWB;
                #pragma unroll
                for (int ks = 0; ks < 4; ++ks) {
                    v8bf A = w3v[(size_t)(((p * 3 + tp) * 4 + ks) * 8 + ct) * 64 + lane];
                    v8bf B = *(const v8bf*)(hrow + ((128 + 2 * (ks * 16 + 8 * lhi5)) ^ swz));
                    a33 = __builtin_amdgcn_mfma_f32_32x32x16_bf16(A, B, a33, 0, 0, 0);
                }
            }
            // --- epilogue: pooling + sigmoid gate ---
            #pragma unroll
            for (int rg = 0; rg < 4; ++rg) {
                int c0 = ct * 32 + 8 * rg + 4 * lhi5;
                float q[5][4];
                #pragma unroll
                for (int d = 0; d < 5; ++d) {
                    int r = s + d;                  // xb row for s_offset d-2
                    u16x4 hv = *(const u16x4*)(xb + r * XB_ROWB + ((2 * c0) ^ ((r & 15) << 4)));
                    #pragma unroll
                    for (int qi = 0; qi < 4; ++qi)
                        q[d][qi] = __uint_as_float((unsigned)hv[qi] << 16);
                }
                #pragma unroll
                for (int qi = 0; qi < 4; ++qi) {
                    int reg = rg * 4 + qi;
                    float xm2 = q[0][qi], xm = q[1][qi], x0 = q[2][qi], xp = q[3][qi], xp2 = q[4][qi];
                    float s3 = (xm + x0 + xp) * (1.f / 3.f);
                    float s5 = (xm2 + xm + x0 + xp + xp2) * 0.2f;
                    float m3 = x0;
                    if (s >= 1)  m3 = fmaxf(m3, xm);
                    if (s <= 62) m3 = fmaxf(m3, xp);
                    float m5 = m3;
                    if (s >= 2)  m5 = fmaxf(m5, xm2);
                    if (s <= 61) m5 = fmaxf(m5, xp2);
                    float s31 = __builtin_amdgcn_rcpf(1.f + __expf(-a31[reg]));
                    float s33 = __builtin_amdgcn_rcpf(1.f + __expf(-a33[reg]));
                    float g = (s3 + m3) * s31 + (s5 + m5) * s33;
                    gm[reg] = fmaxf(gm[reg], g);
                }
            }
        }
        // --- max over s (32 lanes per half) + store ---
        #pragma unroll
        for (int reg = 0; reg < 16; ++reg) {
            float g = gm[reg];
            #pragma unroll
            for (int off = 16; off; off >>= 1) g = fmaxf(g, __shfl_xor(g, off));
            gm[reg] = g;
        }
        if (l31 == 0) {
            float* ob = out + (size_t)pn * 256 + ct * 32 + 4 * lhi5;
            #pragma unroll
            for (int rg = 0; rg < 4; ++rg) {
                float4 o = make_float4(gm[rg * 4], gm[rg * 4 + 1], gm[rg * 4 + 2], gm[rg * 4 + 3]);
                *(float4*)(ob + 8 * rg) = o;
            }
        }
    }
}

// ---------------- fp32 fallback (only if ws too small) ----------------
#define LW 72
__global__ __launch_bounds__(512, 2)
void fused_fallback(const float* __restrict__ x,
                    const float* __restrict__ w31a, const float* __restrict__ w31b,
                    const float* __restrict__ w33a, const float* __restrict__ w33b,
                    float* __restrict__ out) {
    __shared__ float lds[(CC + HH + HH) * LW];
    float* xs = lds;
    float* h31 = lds + CC * LW;
    float* h33 = h31 + HH * LW;
    const int t = threadIdx.x;
    const int n = blockIdx.x, p = blockIdx.y;
    const int lane = t & 63;
    {
        const float4* src = (const float4*)(x + (size_t)(p * NN + n) * (CC * SS));
        #pragma unroll
        for (int i = 0; i < 8; ++i) {
            int f4 = t + i * 512;
            int c = f4 >> 4, q = f4 & 15;
            *(float4*)(xs + c * LW + 4 + q * 4) = src[f4];
        }
        if (t < 256) {
            *(float4*)(xs + t * LW) = make_float4(0.f, 0.f, 0.f, 0.f);
            *(float4*)(xs + t * LW + 68) = make_float4(0.f, 0.f, 0.f, 0.f);
        } else if (t < 320) {
            int h = t - 256;
            *(float4*)(h33 + h * LW) = make_float4(0.f, 0.f, 0.f, 0.f);
            *(float4*)(h33 + h * LW + 68) = make_float4(0.f, 0.f, 0.f, 0.f);
        }
    }
    __syncthreads();
    {
        const int grp = t >> 6;
        const int conv = grp & 1;
        const int hid0 = (grp >> 1) * 16;
        const float4* wa4 = (const float4*)((conv ? w33a : w31a) + (size_t)p * (HH * CC * 3));
        float acc[16];
        #pragma unroll
        for (int h = 0; h < 16; ++h) acc[h] = 0.f;
        for (int c4 = 0; c4 < 64; ++c4) {
            float xm[4], x0[4], xp[4];
            #pragma unroll
            for (int j = 0; j < 4; ++j) {
                const float* r = xs + (c4 * 4 + j) * LW + 4 + lane;
                xm[j] = r[-1]; x0[j] = r[0]; xp[j] = r[1];
            }
            #pragma unroll
            for (int h = 0; h < 16; ++h) {
                const float4* wp = wa4 + (hid0 + h) * 192 + c4 * 3;
                float4 w0 = wp[0], w1 = wp[1], w2 = wp[2];
                float a = acc[h];
                a += xm[0]*w0.x + x0[0]*w0.y + xp[0]*w0.z;
                a += xm[1]*w0.w + x0[1]*w1.x + xp[1]*w1.y;
                a += xm[2]*w1.z + x0[2]*w1.w + xp[2]*w2.x;
                a += xm[3]*w2.y + x0[3]*w2.z + xp[3]*w2.w;
                acc[h] = a;
            }
        }
        float* dst = conv ? h33 : h31;
        #pragma unroll
        for (int h = 0; h < 16; ++h) {
            float v = acc[h];
            v = v >= 0.f ? v : 0.01f * v;
            dst[(hid0 + h) * LW + 4 + lane] = v;
        }
    }
    __syncthreads();
    {
        const int cg = t >> 6;
        const int c0 = cg * 32;
        float l31[32], l33[32];
        #pragma unroll
        for (int i = 0; i < 32; ++i) { l31[i] = 0.f; l33[i] = 0.f; }
        for (int hid = 0; hid < HH; ++hid) {
            const float* hr1 = h31 + hid * LW + 4 + lane;
            const float* hr3 = h33 + hid * LW + 4 + lane;
            float hv = hr1[0];
            float hm = hr3[-1], h0 = hr3[0], hp = hr3[1];
            #pragma unroll
            for (int i = 0; i < 32; ++i) {
                int c = c0 + i;
                l31[i] += hv * w31b[((size_t)p * 256 + c) * 64 + hid];
                const float* wb = w33b + (((size_t)p * 256 + c) * 64 + hid) * 3;
                l33[i] += hm * wb[0] + h0 * wb[1] + hp * wb[2];
            }
        }
        const size_t obase = ((size_t)p * NN + n) * CC + c0;
        #pragma unroll
        for (int i = 0; i < 32; ++i) {
            const float* r = xs + (c0 + i) * LW + 4 + lane;
            float xm2 = r[-2], xm = r[-1], x0v = r[0], xp = r[1], xp2 = r[2];
            float s3 = (xm + x0v + xp) * (1.f / 3.f);
            float s5 = (xm2 + xm + x0v + xp + xp2) * 0.2f;
            float m3 = x0v;
            if (lane >= 1)  m3 = fmaxf(m3, xm);
            if (lane <= 62) m3 = fmaxf(m3, xp);
            float m5 = m3;
            if (lane >= 2)  m5 = fmaxf(m5, xm2);
            if (lane <= 61) m5 = fmaxf(m5, xp2);
            float g = (s3 + m3) / (1.f + __expf(-l31[i])) + (s5 + m5) / (1.f + __expf(-l33[i]));
            #pragma unroll
            for (int off = 32; off; off >>= 1)
                g = fmaxf(g, __shfl_xor(g, off));
            if (lane == 0) out[obase + i] = g;
        }
    }
}

extern "C" void kernel_launch(void* const* d_in, const int* in_sizes, int n_in,
                              void* d_out, int out_size, void* d_ws, size_t ws_size,
                              hipStream_t stream) {
    const float* x    = (const float*)d_in[0];
    const float* w31a = (const float*)d_in[1];
    const float* w31b = (const float*)d_in[2];
    const float* w33a = (const float*)d_in[3];
    const float* w33b = (const float*)d_in[4];
    float* out = (float*)d_out;

    // ws: wp1 @0 (3,145,728 B), wp31 @3,145,728 (524,288 B), wp33 @3,670,016 (1,572,864 B)
    const size_t need = 5242880;
    dim3 grid(NN, PP);
    if (ws_size >= need) {
        unsigned short* wp1  = (unsigned short*)d_ws;
        unsigned short* wp31 = (unsigned short*)((char*)d_ws + 3145728);
        unsigned short* wp33 = (unsigned short*)((char*)d_ws + 3670016);
        k_pack_all<<<512, 256, 0, stream>>>(w31a, w33a, w31b, w33b, wp1, wp31, wp33);
        fused_mfma<<<grid, 512, 0, stream>>>(x, wp1, wp31, wp33, out);
    } else {
        fused_fallback<<<grid, 512, 0, stream>>>(x, w31a, w31b, w33a, w33b, out);
    }
}